// Round 4
// baseline (1388.920 us; speedup 1.0000x reference)
//
#include <hip/hip_runtime.h>
#include <math.h>

#define NN 20000
#define NE 320000
#define D 50
#define TOWERS 5
#define TD 250      // TOWERS*D
#define ASTR 256    // padded row stride for ai/aj (float4-friendly)
#define FOUT 10
#define EPS 1e-5f

// ------------------------------------------------------------------ setup
__global__ void k_deg(const int* __restrict__ dst, int* __restrict__ deg) {
    int e = blockIdx.x * 256 + threadIdx.x;
    if (e < NE) atomicAdd(&deg[dst[e]], 1);
}

__global__ void k_scan(const int* __restrict__ deg, int* __restrict__ offs) {
    __shared__ int buf[1024];
    __shared__ int carry;
    int tid = threadIdx.x;
    if (tid == 0) carry = 0;
    __syncthreads();
    for (int base = 0; base < NN; base += 1024) {
        int i = base + tid;
        int v = (i < NN) ? deg[i] : 0;
        buf[tid] = v;
        __syncthreads();
        for (int off = 1; off < 1024; off <<= 1) {
            int t = (tid >= off) ? buf[tid - off] : 0;
            __syncthreads();
            buf[tid] += t;
            __syncthreads();
        }
        int excl = carry + buf[tid] - v;   // exclusive prefix
        if (i < NN) offs[i] = excl;
        __syncthreads();
        if (tid == 0) carry += buf[1023];
        __syncthreads();
    }
    if (tid == 0) offs[NN] = carry;        // == NE
}

__global__ void k_csr(const int* __restrict__ src, const int* __restrict__ dst,
                      const int* __restrict__ offs, int* __restrict__ cursor,
                      int* __restrict__ csr_src) {
    int e = blockIdx.x * 256 + threadIdx.x;
    if (e < NE) {
        int d = dst[e];
        int slot = atomicAdd(&cursor[d], 1);
        csr_src[offs[d] + slot] = src[e];
    }
}

__global__ void k_avglog(const int* __restrict__ deg, float* __restrict__ accum) {
    int n = blockIdx.x * 256 + threadIdx.x;
    float v = (n < NN) ? logf((float)deg[n] + 1.0f) : 0.0f;
    for (int o = 32; o > 0; o >>= 1) v += __shfl_down(v, o);
    __shared__ float wsum[4];
    int lane = threadIdx.x & 63, w = threadIdx.x >> 6;
    if (lane == 0) wsum[w] = v;
    __syncthreads();
    if (threadIdx.x == 0) atomicAdd(accum, wsum[0] + wsum[1] + wsum[2] + wsum[3]);
}

__global__ void k_emb(const int* __restrict__ x, const float* __restrict__ emb,
                      float* __restrict__ h) {
    int idx = blockIdx.x * 256 + threadIdx.x;
    if (idx < NN * D) {
        int n = idx / D, c = idx % D;
        h[idx] = emb[x[n] * D + c];
    }
}

// ------------------------------------------------------------- per layer
// ai/aj: per-node pre-NN split (x_i part / x_j part), rows padded to ASTR=256
// with zero fill so the aggregation loads unguarded float4s.
#define PRE_NT 64
__global__ __launch_bounds__(256) void k_pre(const float* __restrict__ h,
                                             const float* __restrict__ preW, // [TD][2D]
                                             float* __restrict__ ai,
                                             float* __restrict__ aj) {
    __shared__ float xl[PRE_NT * 52];
    int n0 = blockIdx.x * PRE_NT;
    int nmax = min(PRE_NT, NN - n0);
    for (int k = threadIdx.x; k < nmax * D; k += 256) {
        int nl = k / D, f = k % D;
        xl[nl * 52 + f] = h[(n0 + nl) * D + f];
    }
    __syncthreads();
    int o = threadIdx.x;
    if (o < TD) {
        const float* w0 = preW + o * (2 * D);
        float wi[D], wj[D];
#pragma unroll
        for (int f = 0; f < D; ++f) { wi[f] = w0[f]; wj[f] = w0[D + f]; }
        for (int nl = 0; nl < nmax; ++nl) {
            const float* xv = &xl[nl * 52];
            float a0 = 0.f, a1 = 0.f;
#pragma unroll
            for (int f = 0; f < D; ++f) { a0 += xv[f] * wi[f]; a1 += xv[f] * wj[f]; }
            ai[(size_t)(n0 + nl) * ASTR + o] = a0;
            aj[(size_t)(n0 + nl) * ASTR + o] = a1;
        }
    } else if (o < ASTR) {                    // zero-fill pad columns
        for (int nl = 0; nl < nmax; ++nl) {
            ai[(size_t)(n0 + nl) * ASTR + o] = 0.f;
            aj[(size_t)(n0 + nl) * ASTR + o] = 0.f;
        }
    }
}

// Edge aggregation, feature-sliced for L2 locality. Grid = nodeblocks x 8
// chunks, chunk = blockIdx.x & 7 (XCD-pinned under round-robin dispatch):
// each XCD touches only a 20000 x 128B slice of aj (2.56 MB < 4 MiB L2).
// Block = 512 thr = 8 waves; wave handles 8 nodes x 32 features:
// lane = g*8+q, g = node group, q = float4 within the 32-float chunk.
// Writes RAW stats (no ai/preB base): agg[n][plane][256], planes
// 0=mean,1=min,2=max,3=std. Base added in k_post; std is base-invariant.
__global__ __launch_bounds__(512) void k_agg(
    const float* __restrict__ aj, const int* __restrict__ offs,
    const int* __restrict__ csr_src, float* __restrict__ agg) {
    int chunk = blockIdx.x & 7;
    int nb = blockIdx.x >> 3;
    int tid = threadIdx.x;
    int wave = tid >> 6, lane = tid & 63;
    int g = lane >> 3, q = lane & 7;
    int n = nb * 64 + wave * 8 + g;
    bool node_ok = n < NN;
    int e0 = 0, deg = 0;
    if (node_ok) { e0 = offs[n]; deg = offs[n + 1] - e0; }
    int mdeg = deg;
    mdeg = min(mdeg, __shfl_xor(mdeg, 8));
    mdeg = min(mdeg, __shfl_xor(mdeg, 16));
    mdeg = min(mdeg, __shfl_xor(mdeg, 32));   // wave-min degree

    const float4* ajv = (const float4*)aj;    // row stride 64 float4
    int coloff = chunk * 8 + q;               // float4 column in row
    float s1x = 0.f, s1y = 0.f, s1z = 0.f, s1w = 0.f;
    float s2x = 0.f, s2y = 0.f, s2z = 0.f, s2w = 0.f;
    float mnx = INFINITY, mny = INFINITY, mnz = INFINITY, mnw = INFINITY;
    float mxx = -INFINITY, mxy = -INFINITY, mxz = -INFINITY, mxw = -INFINITY;

    int it = 0;
    for (; it < mdeg; ++it) {                 // unmasked: all groups valid
        int s = csr_src[e0 + it];
        float4 v = ajv[(size_t)s * 64 + coloff];
        s1x += v.x; s1y += v.y; s1z += v.z; s1w += v.w;
        s2x = fmaf(v.x, v.x, s2x); s2y = fmaf(v.y, v.y, s2y);
        s2z = fmaf(v.z, v.z, s2z); s2w = fmaf(v.w, v.w, s2w);
        mnx = fminf(mnx, v.x); mny = fminf(mny, v.y);
        mnz = fminf(mnz, v.z); mnw = fminf(mnw, v.w);
        mxx = fmaxf(mxx, v.x); mxy = fmaxf(mxy, v.y);
        mxz = fmaxf(mxz, v.z); mxw = fmaxf(mxw, v.w);
    }
    while (__any(it < deg)) {                 // masked tail (degree imbalance)
        bool valid = it < deg;
        int ee = valid ? e0 + it : 0;
        int s = csr_src[ee];
        float4 v = ajv[(size_t)s * 64 + coloff];
        float zx = valid ? v.x : 0.f, zy = valid ? v.y : 0.f;
        float zz = valid ? v.z : 0.f, zw = valid ? v.w : 0.f;
        s1x += zx; s1y += zy; s1z += zz; s1w += zw;
        s2x = fmaf(zx, zx, s2x); s2y = fmaf(zy, zy, s2y);
        s2z = fmaf(zz, zz, s2z); s2w = fmaf(zw, zw, s2w);
        mnx = fminf(mnx, valid ? v.x : INFINITY);
        mny = fminf(mny, valid ? v.y : INFINITY);
        mnz = fminf(mnz, valid ? v.z : INFINITY);
        mnw = fminf(mnw, valid ? v.w : INFINITY);
        mxx = fmaxf(mxx, valid ? v.x : -INFINITY);
        mxy = fmaxf(mxy, valid ? v.y : -INFINITY);
        mxz = fmaxf(mxz, valid ? v.z : -INFINITY);
        mxw = fmaxf(mxw, valid ? v.w : -INFINITY);
        ++it;
    }

    if (node_ok) {
        float inv = 1.0f / (float)max(deg, 1);
        float4 m1, mn4, mx4, sd4;
        m1.x = s1x * inv; m1.y = s1y * inv; m1.z = s1z * inv; m1.w = s1w * inv;
        sd4.x = sqrtf(fmaxf(s2x * inv - m1.x * m1.x, 0.f) + EPS);
        sd4.y = sqrtf(fmaxf(s2y * inv - m1.y * m1.y, 0.f) + EPS);
        sd4.z = sqrtf(fmaxf(s2z * inv - m1.z * m1.z, 0.f) + EPS);
        sd4.w = sqrtf(fmaxf(s2w * inv - m1.w * m1.w, 0.f) + EPS);
        if (deg > 0) {
            mn4.x = mnx; mn4.y = mny; mn4.z = mnz; mn4.w = mnw;
            mx4.x = mxx; mx4.y = mxy; mx4.z = mxz; mx4.w = mxw;
        } else {
            m1.x = m1.y = m1.z = m1.w = 0.f;
            mn4.x = mn4.y = mn4.z = mn4.w = 0.f;
            mx4.x = mx4.y = mx4.z = mx4.w = 0.f;
        }
        float4* aggv = (float4*)agg;          // node stride 256 float4
        size_t b = (size_t)n * 256 + coloff;
        aggv[b]       = m1;
        aggv[b + 64]  = mn4;
        aggv[b + 128] = mx4;
        aggv[b + 192] = sd4;
    }
}

// post-NN + lin, reading agg planes from global. Block = 512, 8 nodes.
#define NB 8
__global__ __launch_bounds__(512) void k_post(
    const float* __restrict__ h, const float* __restrict__ ai,
    const float* __restrict__ agg, const int* __restrict__ offs,
    const float* __restrict__ preB,   // [TD]
    const float* __restrict__ postW,  // [T][FOUT][650]
    const float* __restrict__ postB,  // [50]
    const float* __restrict__ linW,   // [50][50]
    const float* __restrict__ linB,   // [50]
    const float* __restrict__ avg_accum, float* __restrict__ hraw) {
    __shared__ float ag[NB * 1000];   // [nl][t*200 + plane*50 + g]
    __shared__ float xr[NB * 52];
    __shared__ float yr[NB * 52];
    __shared__ float scs[NB], iscs[NB];
    __shared__ int degs[NB];
    int n0 = blockIdx.x * NB;
    int tid = threadIdx.x;

    for (int k = tid; k < NB * D; k += 512) {
        int nl = k / D, f = k % D;
        xr[nl * 52 + f] = h[(n0 + nl) * D + f];
    }
    if (tid < NB) {
        int n = n0 + tid;
        int dg = offs[n + 1] - offs[n];
        degs[tid] = dg;
        float cnt = (float)max(dg, 1);
        float avg = avg_accum[0] * (1.0f / NN);
        float sc = logf(cnt + 1.0f) / avg;
        scs[tid] = sc;
        iscs[tid] = 1.0f / sc;
    }
    __syncthreads();

    // stage agg -> LDS, adding base (ai + preB) to mean/min/max when deg>0
    for (int idx = tid; idx < NB * 1000; idx += 512) {
        int nl = idx / 1000, r = idx - nl * 1000;
        int plane = r / 250, f = r - plane * 250;
        int t = f / 50, gg = f - t * 50;
        int n = n0 + nl;
        float val = agg[(size_t)n * 1024 + plane * 256 + f];
        if (plane < 3 && degs[nl] > 0)
            val += ai[(size_t)n * ASTR + f] + preB[f];
        ag[nl * 1000 + t * 200 + plane * 50 + gg] = val;
    }
    __syncthreads();

    // post-NN: y[nl][o] for o=t*10+go; 650-long dot split as x(50)+3x200
    if (tid < NB * 50) {
        int o = tid >> 3, nl = tid & 7;
        int t = o / FOUT;
        const float* w = postW + o * 650;
        const float* ar = &ag[nl * 1000 + t * 200];
        const float* xv = &xr[nl * 52];
        float accx = 0.f;
        const float2* wx = (const float2*)w;
        const float2* xv2 = (const float2*)xv;
#pragma unroll
        for (int j = 0; j < 25; ++j) {
            float2 a2 = xv2[j], b2 = wx[j];
            accx += a2.x * b2.x + a2.y * b2.y;
        }
        float d1 = 0.f, d2 = 0.f, d3 = 0.f;
        const float2* w1 = (const float2*)(w + 50);
        const float2* w2 = (const float2*)(w + 250);
        const float2* w3 = (const float2*)(w + 450);
        const float2* av = (const float2*)ar;
#pragma unroll 4
        for (int j = 0; j < 100; ++j) {
            float2 a2 = av[j];
            float2 b1 = w1[j], b2 = w2[j], b3 = w3[j];
            d1 += b1.x * a2.x + b1.y * a2.y;
            d2 += b2.x * a2.x + b2.y * a2.y;
            d3 += b3.x * a2.x + b3.y * a2.y;
        }
        yr[nl * 52 + o] = postB[o] + accx + d1 + scs[nl] * d2 + iscs[nl] * d3;
    }
    __syncthreads();

    // lin: hraw = y @ linW^T + linB
    if (tid < NB * 50) {
        int nl = tid / 50, c = tid % 50;
        const float* w = linW + c * 50;
        const float* yv = &yr[nl * 52];
        float acc = linB[c];
#pragma unroll
        for (int q = 0; q < 50; ++q) acc += w[q] * yv[q];
        hraw[(n0 + nl) * 50 + c] = acc;
    }
}

__global__ void k_bnstats(const float* __restrict__ hraw, float* __restrict__ bn) {
    __shared__ float ls[50], lq[50];
    for (int k = threadIdx.x; k < 50; k += 256) { ls[k] = 0.f; lq[k] = 0.f; }
    __syncthreads();
    for (int idx = blockIdx.x * 256 + threadIdx.x; idx < NN * D; idx += gridDim.x * 256) {
        float v = hraw[idx];
        int c = idx % D;
        atomicAdd(&ls[c], v);
        atomicAdd(&lq[c], v * v);
    }
    __syncthreads();
    for (int k = threadIdx.x; k < 50; k += 256) {
        atomicAdd(&bn[k], ls[k]);
        atomicAdd(&bn[50 + k], lq[k]);
    }
}

__global__ void k_bnapply(const float* __restrict__ hraw, const float* __restrict__ bn,
                          const float* __restrict__ gamma, const float* __restrict__ beta,
                          float* __restrict__ h) {
    int idx = blockIdx.x * 256 + threadIdx.x;
    if (idx < NN * D) {
        int c = idx % D;
        float mean = bn[c] * (1.0f / NN);
        float var = bn[50 + c] * (1.0f / NN) - mean * mean;
        float v = gamma[c] * (hraw[idx] - mean) * rsqrtf(var + EPS) + beta[c];
        h[idx] = fmaxf(v, 0.f);
    }
}

__global__ void k_mlp(const float* __restrict__ h, const float* __restrict__ W1,
                      const float* __restrict__ b1, const float* __restrict__ W2,
                      const float* __restrict__ b2, float* __restrict__ out) {
    int n = blockIdx.x * 256 + threadIdx.x;
    if (n >= NN) return;
    float hv[50];
#pragma unroll
    for (int f = 0; f < 50; ++f) hv[f] = h[n * 50 + f];
    float s = b2[0];
    for (int o = 0; o < 25; ++o) {
        float a = b1[o];
        const float* w = W1 + o * 50;
#pragma unroll
        for (int f = 0; f < 50; ++f) a += w[f] * hv[f];
        s += W2[o] * fmaxf(a, 0.f);
    }
    out[n] = 1.0f / (1.0f + expf(-s));
}

// ------------------------------------------------------------------ launch
extern "C" void kernel_launch(void* const* d_in, const int* in_sizes, int n_in,
                              void* d_out, int out_size, void* d_ws, size_t ws_size,
                              hipStream_t stream) {
    const int* x = (const int*)d_in[0];
    const int* ei = (const int*)d_in[1];
    const int* src = ei;
    const int* dst = ei + NE;
    const float* emb   = (const float*)d_in[4];
    const float* preW  = (const float*)d_in[5];
    const float* preB  = (const float*)d_in[6];
    const float* postW = (const float*)d_in[7];
    const float* postB = (const float*)d_in[8];
    const float* linW  = (const float*)d_in[9];
    const float* linB  = (const float*)d_in[10];
    const float* gamma = (const float*)d_in[11];
    const float* beta  = (const float*)d_in[12];
    const float* W1 = (const float*)d_in[13];
    const float* b1 = (const float*)d_in[14];
    const float* W2 = (const float*)d_in[15];
    const float* b2 = (const float*)d_in[16];
    float* outp = (float*)d_out;

    char* wsp = (char*)d_ws;
    size_t off = 0;
    auto alloc = [&](size_t bytes) {
        void* p = wsp + off;
        off = (off + bytes + 1023) & ~(size_t)1023;
        return p;
    };
    int* deg    = (int*)alloc(NN * 4);
    int* cursor = (int*)alloc(NN * 4);
    int* offs   = (int*)alloc((NN + 1) * 4);
    int* csr    = (int*)alloc(NE * 4);
    float* bn   = (float*)alloc(512);          // [0:50) sum, [50:100) sq, [100] avg_log
    float* h    = (float*)alloc((size_t)NN * D * 4);
    float* hraw = (float*)alloc((size_t)NN * D * 4);
    float* ai   = (float*)alloc((size_t)NN * ASTR * 4);
    float* aj   = (float*)alloc((size_t)NN * ASTR * 4);
    float* agg  = (float*)alloc((size_t)NN * 1024 * 4);  // [NN][4][256] raw stats
    (void)ws_size; (void)in_sizes; (void)n_in; (void)out_size;

    hipMemsetAsync(deg, 0, NN * 4, stream);
    hipMemsetAsync(cursor, 0, NN * 4, stream);
    hipMemsetAsync(bn, 0, 512, stream);

    k_deg<<<(NE + 255) / 256, 256, 0, stream>>>(dst, deg);
    k_scan<<<1, 1024, 0, stream>>>(deg, offs);
    k_csr<<<(NE + 255) / 256, 256, 0, stream>>>(src, dst, offs, cursor, csr);
    k_avglog<<<(NN + 255) / 256, 256, 0, stream>>>(deg, bn + 100);
    k_emb<<<(NN * D + 255) / 256, 256, 0, stream>>>(x, emb, h);

    int aggblocks = ((NN + 63) / 64) * 8;     // nodeblocks x 8 chunks
    for (int l = 0; l < 4; ++l) {
        k_pre<<<(NN + PRE_NT - 1) / PRE_NT, 256, 0, stream>>>(h, preW + l * TD * 100, ai, aj);
        k_agg<<<aggblocks, 512, 0, stream>>>(aj, offs, csr, agg);
        k_post<<<NN / NB, 512, 0, stream>>>(h, ai, agg, offs,
                                            preB + l * TD, postW + l * 32500,
                                            postB + l * 50, linW + l * 2500,
                                            linB + l * 50, bn + 100, hraw);
        hipMemsetAsync(bn, 0, 400, stream);   // keep bn[100] (avg_log) intact
        k_bnstats<<<200, 256, 0, stream>>>(hraw, bn);
        k_bnapply<<<(NN * D + 255) / 256, 256, 0, stream>>>(hraw, bn, gamma + l * 50,
                                                            beta + l * 50, h);
    }
    k_mlp<<<(NN + 255) / 256, 256, 0, stream>>>(h, W1, b1, W2, b2, outp);
}

// Round 5
// 1109.473 us; speedup vs baseline: 1.2519x; 1.2519x over previous
//
#include <hip/hip_runtime.h>
#include <math.h>

#define NN 20000
#define NE 320000
#define D 50
#define TOWERS 5
#define TD 250      // TOWERS*D
#define ASTR 256    // padded row stride for ai/aj (float4-friendly)
#define AGGSTR 1000 // packed agg row: [t*200 + plane*50 + g]
#define FOUT 10
#define EPS 1e-5f

// ------------------------------------------------------------------ setup
__global__ void k_deg(const int* __restrict__ dst, int* __restrict__ deg) {
    int e = blockIdx.x * 256 + threadIdx.x;
    if (e < NE) atomicAdd(&deg[dst[e]], 1);
}

__global__ void k_scan(const int* __restrict__ deg, int* __restrict__ offs) {
    __shared__ int buf[1024];
    __shared__ int carry;
    int tid = threadIdx.x;
    if (tid == 0) carry = 0;
    __syncthreads();
    for (int base = 0; base < NN; base += 1024) {
        int i = base + tid;
        int v = (i < NN) ? deg[i] : 0;
        buf[tid] = v;
        __syncthreads();
        for (int off = 1; off < 1024; off <<= 1) {
            int t = (tid >= off) ? buf[tid - off] : 0;
            __syncthreads();
            buf[tid] += t;
            __syncthreads();
        }
        int excl = carry + buf[tid] - v;   // exclusive prefix
        if (i < NN) offs[i] = excl;
        __syncthreads();
        if (tid == 0) carry += buf[1023];
        __syncthreads();
    }
    if (tid == 0) offs[NN] = carry;        // == NE
}

__global__ void k_csr(const int* __restrict__ src, const int* __restrict__ dst,
                      const int* __restrict__ offs, int* __restrict__ cursor,
                      int* __restrict__ csr_src) {
    int e = blockIdx.x * 256 + threadIdx.x;
    if (e < NE) {
        int d = dst[e];
        int slot = atomicAdd(&cursor[d], 1);
        csr_src[offs[d] + slot] = src[e];
    }
}

__global__ void k_avglog(const int* __restrict__ deg, float* __restrict__ accum) {
    int n = blockIdx.x * 256 + threadIdx.x;
    float v = (n < NN) ? logf((float)deg[n] + 1.0f) : 0.0f;
    for (int o = 32; o > 0; o >>= 1) v += __shfl_down(v, o);
    __shared__ float wsum[4];
    int lane = threadIdx.x & 63, w = threadIdx.x >> 6;
    if (lane == 0) wsum[w] = v;
    __syncthreads();
    if (threadIdx.x == 0) atomicAdd(accum, wsum[0] + wsum[1] + wsum[2] + wsum[3]);
}

__global__ void k_emb(const int* __restrict__ x, const float* __restrict__ emb,
                      float* __restrict__ h) {
    int idx = blockIdx.x * 256 + threadIdx.x;
    if (idx < NN * D) {
        int n = idx / D, c = idx % D;
        h[idx] = emb[x[n] * D + c];
    }
}

// ------------------------------------------------------------- per layer
#define PRE_NT 64
__global__ __launch_bounds__(256) void k_pre(const float* __restrict__ h,
                                             const float* __restrict__ preW, // [TD][2D]
                                             float* __restrict__ ai,
                                             float* __restrict__ aj) {
    __shared__ float xl[PRE_NT * 52];
    int n0 = blockIdx.x * PRE_NT;
    int nmax = min(PRE_NT, NN - n0);
    for (int k = threadIdx.x; k < nmax * D; k += 256) {
        int nl = k / D, f = k % D;
        xl[nl * 52 + f] = h[(n0 + nl) * D + f];
    }
    __syncthreads();
    int o = threadIdx.x;
    if (o < TD) {
        const float* w0 = preW + o * (2 * D);
        float wi[D], wj[D];
#pragma unroll
        for (int f = 0; f < D; ++f) { wi[f] = w0[f]; wj[f] = w0[D + f]; }
        for (int nl = 0; nl < nmax; ++nl) {
            const float* xv = &xl[nl * 52];
            float a0 = 0.f, a1 = 0.f;
#pragma unroll
            for (int f = 0; f < D; ++f) { a0 += xv[f] * wi[f]; a1 += xv[f] * wj[f]; }
            ai[(size_t)(n0 + nl) * ASTR + o] = a0;
            aj[(size_t)(n0 + nl) * ASTR + o] = a1;
        }
    } else if (o < ASTR) {                    // zero-fill pad columns
        for (int nl = 0; nl < nmax; ++nl) {
            ai[(size_t)(n0 + nl) * ASTR + o] = 0.f;
            aj[(size_t)(n0 + nl) * ASTR + o] = 0.f;
        }
    }
}

// Edge aggregation, feature-sliced for L2 locality (chunk = blockIdx.x & 7).
// Wave handles 8 nodes x 32 features (lane = g*8+q). Writes PACKED agg rows
// [n][t*200 + plane*50 + g] with the (ai + preB) base already folded into
// mean/min/max (skipped when deg==0, matching torch_scatter empty fill).
__global__ __launch_bounds__(512) void k_agg(
    const float* __restrict__ aj, const int* __restrict__ offs,
    const int* __restrict__ csr_src, const float* __restrict__ ai,
    const float* __restrict__ preB, float* __restrict__ agg) {
    int chunk = blockIdx.x & 7;
    int nb = blockIdx.x >> 3;
    int tid = threadIdx.x;
    int wave = tid >> 6, lane = tid & 63;
    int g = lane >> 3, q = lane & 7;
    int n = nb * 64 + wave * 8 + g;
    bool node_ok = n < NN;
    int e0 = 0, deg = 0;
    if (node_ok) { e0 = offs[n]; deg = offs[n + 1] - e0; }
    int mdeg = deg;
    mdeg = min(mdeg, __shfl_xor(mdeg, 8));
    mdeg = min(mdeg, __shfl_xor(mdeg, 16));
    mdeg = min(mdeg, __shfl_xor(mdeg, 32));   // wave-min degree

    const float4* ajv = (const float4*)aj;    // row stride 64 float4
    int coloff = chunk * 8 + q;               // float4 column in row
    float s1x = 0.f, s1y = 0.f, s1z = 0.f, s1w = 0.f;
    float s2x = 0.f, s2y = 0.f, s2z = 0.f, s2w = 0.f;
    float mnx = INFINITY, mny = INFINITY, mnz = INFINITY, mnw = INFINITY;
    float mxx = -INFINITY, mxy = -INFINITY, mxz = -INFINITY, mxw = -INFINITY;

    int it = 0;
    for (; it < mdeg; ++it) {                 // unmasked: all groups valid
        int s = csr_src[e0 + it];
        float4 v = ajv[(size_t)s * 64 + coloff];
        s1x += v.x; s1y += v.y; s1z += v.z; s1w += v.w;
        s2x = fmaf(v.x, v.x, s2x); s2y = fmaf(v.y, v.y, s2y);
        s2z = fmaf(v.z, v.z, s2z); s2w = fmaf(v.w, v.w, s2w);
        mnx = fminf(mnx, v.x); mny = fminf(mny, v.y);
        mnz = fminf(mnz, v.z); mnw = fminf(mnw, v.w);
        mxx = fmaxf(mxx, v.x); mxy = fmaxf(mxy, v.y);
        mxz = fmaxf(mxz, v.z); mxw = fmaxf(mxw, v.w);
    }
    while (__any(it < deg)) {                 // masked tail (degree imbalance)
        bool valid = it < deg;
        int ee = valid ? e0 + it : 0;
        int s = csr_src[ee];
        float4 v = ajv[(size_t)s * 64 + coloff];
        float zx = valid ? v.x : 0.f, zy = valid ? v.y : 0.f;
        float zz = valid ? v.z : 0.f, zw = valid ? v.w : 0.f;
        s1x += zx; s1y += zy; s1z += zz; s1w += zw;
        s2x = fmaf(zx, zx, s2x); s2y = fmaf(zy, zy, s2y);
        s2z = fmaf(zz, zz, s2z); s2w = fmaf(zw, zw, s2w);
        mnx = fminf(mnx, valid ? v.x : INFINITY);
        mny = fminf(mny, valid ? v.y : INFINITY);
        mnz = fminf(mnz, valid ? v.z : INFINITY);
        mnw = fminf(mnw, valid ? v.w : INFINITY);
        mxx = fmaxf(mxx, valid ? v.x : -INFINITY);
        mxy = fmaxf(mxy, valid ? v.y : -INFINITY);
        mxz = fmaxf(mxz, valid ? v.z : -INFINITY);
        mxw = fmaxf(mxw, valid ? v.w : -INFINITY);
        ++it;
    }

    if (node_ok) {
        float inv = 1.0f / (float)max(deg, 1);
        float m1a[4], mna[4], mxa[4], sda[4];
        m1a[0] = s1x * inv; m1a[1] = s1y * inv; m1a[2] = s1z * inv; m1a[3] = s1w * inv;
        sda[0] = sqrtf(fmaxf(s2x * inv - m1a[0] * m1a[0], 0.f) + EPS);
        sda[1] = sqrtf(fmaxf(s2y * inv - m1a[1] * m1a[1], 0.f) + EPS);
        sda[2] = sqrtf(fmaxf(s2z * inv - m1a[2] * m1a[2], 0.f) + EPS);
        sda[3] = sqrtf(fmaxf(s2w * inv - m1a[3] * m1a[3], 0.f) + EPS);
        mna[0] = mnx; mna[1] = mny; mna[2] = mnz; mna[3] = mnw;
        mxa[0] = mxx; mxa[1] = mxy; mxa[2] = mxz; mxa[3] = mxw;
        int f0 = coloff * 4;
        float4 aiv = ((const float4*)ai)[(size_t)n * 64 + coloff];
        float aia[4] = {aiv.x, aiv.y, aiv.z, aiv.w};
#pragma unroll
        for (int k = 0; k < 4; ++k) {
            int f = f0 + k;
            if (f < TD) {
                float base;
                if (deg > 0) {
                    base = aia[k] + preB[f];
                } else {
                    base = 0.f;
                    m1a[k] = 0.f; mna[k] = 0.f; mxa[k] = 0.f;
                    // sda[k] already sqrt(EPS)
                }
                int t = f / 50, gg = f - t * 50;
                float* row = agg + (size_t)n * AGGSTR + t * 200 + gg;
                row[0]   = m1a[k] + base;
                row[50]  = mna[k] + base;
                row[100] = mxa[k] + base;
                row[150] = sda[k];
            }
        }
    }
}

// post-NN + lin + BN-stats. 16 nodes/block, 512 threads.
// Phase 1: stage agg (float4 copy) + x + scalers. Phase 2: dots — threads
// (p in 0..2, o in 0..49, half) each stream one 200-float w row over 8 nodes;
// threads 300..349 do the x(50) part for all 16 nodes. Phase 3: combine with
// sc/isc. Phase 4: 50x50 lin + LDS-binned BN partial sums.
#define NT 16
__global__ __launch_bounds__(512) void k_post(
    const float* __restrict__ h, const float* __restrict__ agg,
    const int* __restrict__ offs,
    const float* __restrict__ postW,  // [T][FOUT][650]
    const float* __restrict__ postB,  // [50]
    const float* __restrict__ linW,   // [50][50]
    const float* __restrict__ linB,   // [50]
    const float* __restrict__ avg_accum, float* __restrict__ hraw,
    float* __restrict__ bn) {
    __shared__ float ag[NT * AGGSTR];   // 64 KB; reused as yr after dots
    __shared__ float xr[NT * 50];
    __shared__ float dp[4][NT][50];     // partial dots: d1,d2,d3,x
    __shared__ float scs[NT], iscs[NT];
    __shared__ float bnl[100];
    int n0 = blockIdx.x * NT;
    int tid = threadIdx.x;

    const float4* av4 = (const float4*)(agg + (size_t)n0 * AGGSTR);
    float4* ag4 = (float4*)ag;
    for (int i = tid; i < NT * (AGGSTR / 4); i += 512) ag4[i] = av4[i];
    for (int i = tid; i < NT * 50; i += 512) {
        int nl = i / 50, f = i - nl * 50;
        xr[i] = h[(n0 + nl) * 50 + f];
    }
    if (tid < NT) {
        int n = n0 + tid;
        int dg = offs[n + 1] - offs[n];
        float cnt = (float)max(dg, 1);
        float avg = avg_accum[0] * (1.0f / NN);
        float sc = logf(cnt + 1.0f) / avg;
        scs[tid] = sc;
        iscs[tid] = 1.0f / sc;
    }
    if (tid < 100) bnl[tid] = 0.f;
    __syncthreads();

    if (tid < 300) {                    // agg dots: (p, o, half) -> 8 nodes
        int p = tid / 100;
        int r = tid - p * 100;
        int o = r >> 1, half = r & 1;
        int t = o / FOUT;
        const float2* w2 = (const float2*)(postW + o * 650 + 50 + p * 200);
        int nb = half * 8;
        float acc[8];
#pragma unroll
        for (int i = 0; i < 8; ++i) acc[i] = 0.f;
        const float* agt = ag + t * 200;
#pragma unroll 2
        for (int j = 0; j < 50; ++j) {
            float2 wa = w2[2 * j], wb = w2[2 * j + 1];
#pragma unroll
            for (int i = 0; i < 8; ++i) {
                float4 a = *(const float4*)&agt[(nb + i) * AGGSTR + 4 * j];
                acc[i] += a.x * wa.x + a.y * wa.y + a.z * wb.x + a.w * wb.y;
            }
        }
#pragma unroll
        for (int i = 0; i < 8; ++i) dp[p][nb + i][o] = acc[i];
    } else if (tid < 350) {             // x part: o -> all 16 nodes
        int o = tid - 300;
        const float2* w2 = (const float2*)(postW + o * 650);
        float acc[NT];
#pragma unroll
        for (int i = 0; i < NT; ++i) acc[i] = 0.f;
        for (int j = 0; j < 25; ++j) {
            float2 w = w2[j];
#pragma unroll
            for (int nl = 0; nl < NT; ++nl) {
                float2 xv = *(const float2*)&xr[nl * 50 + 2 * j];
                acc[nl] += xv.x * w.x + xv.y * w.y;
            }
        }
#pragma unroll
        for (int nl = 0; nl < NT; ++nl) dp[3][nl][o] = acc[nl];
    }
    __syncthreads();

    float* yr = ag;                     // ag is dead; reuse as y buffer
    for (int k = tid; k < NT * 50; k += 512) {
        int nl = k / 50, o = k - nl * 50;
        yr[k] = postB[o] + dp[0][nl][o] + scs[nl] * dp[1][nl][o]
              + iscs[nl] * dp[2][nl][o] + dp[3][nl][o];
    }
    __syncthreads();

    for (int k = tid; k < NT * 50; k += 512) {
        int nl = k / 50, c = k - nl * 50;
        const float2* w2 = (const float2*)(linW + c * 50);
        const float2* yv = (const float2*)(yr + nl * 50);
        float acc = linB[c];
#pragma unroll
        for (int q = 0; q < 25; ++q) {
            float2 a = yv[q], b = w2[q];
            acc += a.x * b.x + a.y * b.y;
        }
        hraw[(n0 + nl) * 50 + c] = acc;
        atomicAdd(&bnl[c], acc);
        atomicAdd(&bnl[50 + c], acc * acc);
    }
    __syncthreads();
    if (tid < 100) atomicAdd(&bn[tid], bnl[tid]);
}

__global__ void k_bnapply(const float* __restrict__ hraw, const float* __restrict__ bn,
                          const float* __restrict__ gamma, const float* __restrict__ beta,
                          float* __restrict__ h) {
    int idx = blockIdx.x * 256 + threadIdx.x;
    if (idx < NN * D) {
        int c = idx % D;
        float mean = bn[c] * (1.0f / NN);
        float var = bn[50 + c] * (1.0f / NN) - mean * mean;
        float v = gamma[c] * (hraw[idx] - mean) * rsqrtf(var + EPS) + beta[c];
        h[idx] = fmaxf(v, 0.f);
    }
}

__global__ void k_mlp(const float* __restrict__ h, const float* __restrict__ W1,
                      const float* __restrict__ b1, const float* __restrict__ W2,
                      const float* __restrict__ b2, float* __restrict__ out) {
    int n = blockIdx.x * 256 + threadIdx.x;
    if (n >= NN) return;
    float hv[50];
#pragma unroll
    for (int f = 0; f < 50; ++f) hv[f] = h[n * 50 + f];
    float s = b2[0];
    for (int o = 0; o < 25; ++o) {
        float a = b1[o];
        const float* w = W1 + o * 50;
#pragma unroll
        for (int f = 0; f < 50; ++f) a += w[f] * hv[f];
        s += W2[o] * fmaxf(a, 0.f);
    }
    out[n] = 1.0f / (1.0f + expf(-s));
}

// ------------------------------------------------------------------ launch
extern "C" void kernel_launch(void* const* d_in, const int* in_sizes, int n_in,
                              void* d_out, int out_size, void* d_ws, size_t ws_size,
                              hipStream_t stream) {
    const int* x = (const int*)d_in[0];
    const int* ei = (const int*)d_in[1];
    const int* src = ei;
    const int* dst = ei + NE;
    const float* emb   = (const float*)d_in[4];
    const float* preW  = (const float*)d_in[5];
    const float* preB  = (const float*)d_in[6];
    const float* postW = (const float*)d_in[7];
    const float* postB = (const float*)d_in[8];
    const float* linW  = (const float*)d_in[9];
    const float* linB  = (const float*)d_in[10];
    const float* gamma = (const float*)d_in[11];
    const float* beta  = (const float*)d_in[12];
    const float* W1 = (const float*)d_in[13];
    const float* b1 = (const float*)d_in[14];
    const float* W2 = (const float*)d_in[15];
    const float* b2 = (const float*)d_in[16];
    float* outp = (float*)d_out;

    char* wsp = (char*)d_ws;
    size_t off = 0;
    auto alloc = [&](size_t bytes) {
        void* p = wsp + off;
        off = (off + bytes + 1023) & ~(size_t)1023;
        return p;
    };
    int* deg    = (int*)alloc(NN * 4);
    int* cursor = (int*)alloc(NN * 4);
    int* offs   = (int*)alloc((NN + 1) * 4);
    int* csr    = (int*)alloc(NE * 4);
    float* bn   = (float*)alloc(512);          // [0:50) sum, [50:100) sq, [100] avg_log
    float* h    = (float*)alloc((size_t)NN * D * 4);
    float* hraw = (float*)alloc((size_t)NN * D * 4);
    float* ai   = (float*)alloc((size_t)NN * ASTR * 4);
    float* aj   = (float*)alloc((size_t)NN * ASTR * 4);
    float* agg  = (float*)alloc((size_t)NN * AGGSTR * 4);  // packed stats+base
    (void)ws_size; (void)in_sizes; (void)n_in; (void)out_size;

    hipMemsetAsync(deg, 0, NN * 4, stream);
    hipMemsetAsync(cursor, 0, NN * 4, stream);
    hipMemsetAsync(bn, 0, 512, stream);

    k_deg<<<(NE + 255) / 256, 256, 0, stream>>>(dst, deg);
    k_scan<<<1, 1024, 0, stream>>>(deg, offs);
    k_csr<<<(NE + 255) / 256, 256, 0, stream>>>(src, dst, offs, cursor, csr);
    k_avglog<<<(NN + 255) / 256, 256, 0, stream>>>(deg, bn + 100);
    k_emb<<<(NN * D + 255) / 256, 256, 0, stream>>>(x, emb, h);

    int aggblocks = ((NN + 63) / 64) * 8;     // nodeblocks x 8 chunks
    for (int l = 0; l < 4; ++l) {
        k_pre<<<(NN + PRE_NT - 1) / PRE_NT, 256, 0, stream>>>(h, preW + l * TD * 100, ai, aj);
        k_agg<<<aggblocks, 512, 0, stream>>>(aj, offs, csr, ai, preB + l * TD, agg);
        hipMemsetAsync(bn, 0, 400, stream);   // keep bn[100] (avg_log) intact
        k_post<<<NN / NT, 512, 0, stream>>>(h, agg, offs,
                                            postW + l * 32500, postB + l * 50,
                                            linW + l * 2500, linB + l * 50,
                                            bn + 100, hraw, bn);
        k_bnapply<<<(NN * D + 255) / 256, 256, 0, stream>>>(hraw, bn, gamma + l * 50,
                                                            beta + l * 50, h);
    }
    k_mlp<<<(NN + 255) / 256, 256, 0, stream>>>(h, W1, b1, W2, b2, outp);
}